// Round 13
// baseline (123.456 us; speedup 1.0000x reference)
//
#include <hip/hip_runtime.h>

#define NN 50000
#define NE 800000
#define ETOT (NE + NN)           // 850000 incl. self-loops
#define INCH 128
#define OUTC 64
#define LOG2E 1.44269504088896f
#define NBK 196                  // dst buckets (dst>>8), 256 nodes each
#define BCAP 5120                // bucket capacity (avg 4352, sigma 64)
#define EPB 1024                 // edges per binA block
#define BTH 1024                 // binB block size

// ---------------- workspace layout (bytes) ----------------
// hbuf  : uint[NN*64]     @ 0           (12,800,000)  packed bf16 (h0 lo, h1 hi)
// asrc  : float2[NN]      @ 12,800,000  (400,000)     (pre-scaled by log2e)
// adst  : float2[NN]      @ 13,200,000  (400,000)     (pre-scaled by log2e)
// gbc   : int[NBK]        @ 13,600,000  (1,024)       (zeroed by k_proj blk 0)
// bbase : int[NBK+1]      @ 13,601,024  (1,024)
// off   : int[NN+1]       @ 13,602,048  (200,004)
// cnt   : int[NN]         @ 13,802,052  (200,000)     (zeroed by k_proj)
// srcs16: ushort[ETOT]    @ 14,002,052  (1,700,000)
// wpk   : uint[ETOT]      @ 15,702,052  (3,400,000)   packed bf16 (w0 lo, w1 hi)
// binb  : uint[NBK*BCAP]  @ 19,102,052  (4,014,080)   s | (d&255)<<16
#define OFF_HBUF  0
#define OFF_ASRC  12800000
#define OFF_ADST  13200000
#define OFF_GBC   13600000
#define OFF_BBASE 13601024
#define OFF_OFF   13602048
#define OFF_CNT   13802052
#define OFF_SRC16 14002052
#define OFF_WPK   15702052
#define OFF_BINB  19102052

typedef __attribute__((ext_vector_type(8))) short short8v;   // 8 bf16 (4 VGPR)
typedef __attribute__((ext_vector_type(4))) float float4v;   // MFMA acc
typedef unsigned long long ull;

__device__ __forceinline__ unsigned short f2bf(float f) {
    unsigned u = __float_as_uint(f);
    u += 0x7fffu + ((u >> 16) & 1u);   // round-to-nearest-even
    return (unsigned short)(u >> 16);
}
__device__ __forceinline__ unsigned packbf(float a, float b) {
    return (unsigned)f2bf(a) | ((unsigned)f2bf(b) << 16);
}

// ---------------------------------------------------------------------------
// MFMA projection: h = x@W (bf16 in, fp32 acc), packed bf16 hbuf out
// (interleaved [node][64ch]), attention dots pre-scaled by log2e.
// Also zeroes gbc (block 0) and this block's 64 cnt entries.
// ---------------------------------------------------------------------------
#define PITCH 272
#define XLDS_BYTES (64 * PITCH)
#define WT_OFF XLDS_BYTES
#define SMEM_BYTES (XLDS_BYTES + 128 * PITCH)  // 52224

__global__ __launch_bounds__(256) void k_proj(const float* __restrict__ x,
                                              const float* __restrict__ W,
                                              const float* __restrict__ att_src,
                                              const float* __restrict__ att_dst,
                                              unsigned* __restrict__ hbuf,
                                              float2* __restrict__ asrc,
                                              float2* __restrict__ adst,
                                              int* __restrict__ gbc,
                                              int* __restrict__ cnt) {
    __shared__ char smem[SMEM_BYTES];
    const int t = threadIdx.x;
    const int nbase = blockIdx.x * 64;

    if (blockIdx.x == 0 && t < NBK) gbc[t] = 0;
    if (t < 64 && nbase + t < NN) cnt[nbase + t] = 0;

    // ---- stage x-tile (64 rows x 128 k) as bf16, pitch 272 ----
    {
        const int rl = t >> 2;
        const int q  = t & 3;
        int rg = nbase + rl;
        if (rg >= NN) rg = NN - 1;
        const float4* src = (const float4*)(x + (size_t)rg * INCH + q * 32);
        char* dst = smem + rl * PITCH + q * 64;
#pragma unroll
        for (int i = 0; i < 8; ++i) {
            const float4 v = src[i];
            const unsigned lo = packbf(v.x, v.y);
            const unsigned hi = packbf(v.z, v.w);
            *(ull*)(dst + i * 8) = (ull)lo | ((ull)hi << 32);
        }
    }
    // ---- stage W^T (128 cols x 128 k) as bf16, pitch 272 ----
    {
        const int c  = t & 127;
        const int kh = t >> 7;
        const float* wcol = W + c;
        char* dst = smem + WT_OFF + c * PITCH + kh * 128;
#pragma unroll
        for (int i = 0; i < 16; ++i) {
            const int k = kh * 64 + i * 4;
            const float w0 = wcol[(size_t)(k + 0) * 128];
            const float w1 = wcol[(size_t)(k + 1) * 128];
            const float w2 = wcol[(size_t)(k + 2) * 128];
            const float w3 = wcol[(size_t)(k + 3) * 128];
            const unsigned lo = packbf(w0, w1);
            const unsigned hi = packbf(w2, w3);
            *(ull*)(dst + i * 8) = (ull)lo | ((ull)hi << 32);
        }
    }
    __syncthreads();

    const int w  = t >> 6;
    const int l  = t & 63;
    const int li = l & 15;
    const int g  = l >> 4;

    const char* xb = smem + (w * 16 + li) * PITCH + g * 16;
    const char* wb = smem + WT_OFF + li * PITCH + g * 16;

    float4v acc[8] = {};
#pragma unroll
    for (int ks = 0; ks < 4; ++ks) {
        const short8v aF = *(const short8v*)(xb + ks * 64);
#pragma unroll
        for (int nt = 0; nt < 8; ++nt) {
            const short8v bF = *(const short8v*)(wb + nt * (16 * PITCH) + ks * 64);
            acc[nt] = __builtin_amdgcn_mfma_f32_16x16x32_bf16(aF, bF, acc[nt], 0, 0, 0);
        }
    }

    float aS0[4], aS1[4], aD0[4], aD1[4];
#pragma unroll
    for (int tt = 0; tt < 4; ++tt) {
        aS0[tt] = att_src[tt * 16 + li];
        aS1[tt] = att_src[64 + tt * 16 + li];
        aD0[tt] = att_dst[tt * 16 + li];
        aD1[tt] = att_dst[64 + tt * 16 + li];
    }
#pragma unroll
    for (int r = 0; r < 4; ++r) {
        const int n = nbase + w * 16 + g * 4 + r;
        const bool valid = (n < NN);
        float ps0 = 0.f, ps1 = 0.f, pd0 = 0.f, pd1 = 0.f;
#pragma unroll
        for (int tt = 0; tt < 4; ++tt) {
            const float h0 = acc[tt][r];
            const float h1 = acc[tt + 4][r];
            if (valid) hbuf[(size_t)n * 64 + tt * 16 + li] = packbf(h0, h1);
            ps0 += h0 * aS0[tt];
            ps1 += h1 * aS1[tt];
            pd0 += h0 * aD0[tt];
            pd1 += h1 * aD1[tt];
        }
#pragma unroll
        for (int m = 1; m <= 8; m <<= 1) {
            ps0 += __shfl_xor(ps0, m);
            ps1 += __shfl_xor(ps1, m);
            pd0 += __shfl_xor(pd0, m);
            pd1 += __shfl_xor(pd1, m);
        }
        if (valid && li == 0) {
            asrc[n] = make_float2(ps0 * LOG2E, ps1 * LOG2E);
            adst[n] = make_float2(pd0 * LOG2E, pd1 * LOG2E);
        }
    }
}

// ---------------------------------------------------------------------------
// binA: single pass — edges cached in registers, LDS bucket histogram +
// per-node global cnt, reserve chunks in gbc, write packed uint
// (s | dlow<<16) into bucket regions.
// ---------------------------------------------------------------------------
__global__ __launch_bounds__(256) void k_binA(const int* __restrict__ ei,
                                              int* __restrict__ gbc,
                                              int* __restrict__ cnt,
                                              unsigned* __restrict__ binb) {
    __shared__ int lcnt[NBK];
    __shared__ int lbase[NBK];
    const int t = threadIdx.x;
    const int e0 = blockIdx.x * EPB;

    for (int i = t; i < NBK; i += 256) lcnt[i] = 0;
    __syncthreads();

    int sr[EPB / 256], dr[EPB / 256];
#pragma unroll
    for (int k = 0; k < EPB / 256; ++k) {
        const int e = e0 + k * 256 + t;
        if (e < ETOT) {
            int s, d;
            if (e < NE) { s = ei[e]; d = ei[NE + e]; }
            else        { s = d = e - NE; }
            sr[k] = s; dr[k] = d;
            atomicAdd(&lcnt[d >> 8], 1);
            atomicAdd(&cnt[d], 1);          // per-node in-degree (for binB scan)
        } else {
            sr[k] = -1; dr[k] = 0;
        }
    }
    __syncthreads();
    for (int i = t; i < NBK; i += 256) {
        const int c = lcnt[i];
        lbase[i] = c ? atomicAdd(&gbc[i], c) : 0;
        lcnt[i] = 0;
    }
    __syncthreads();
#pragma unroll
    for (int k = 0; k < EPB / 256; ++k) {
        if (sr[k] >= 0) {
            const int b = dr[k] >> 8;
            const int r = lbase[b] + atomicAdd(&lcnt[b], 1);
            if (r < BCAP)
                binb[(size_t)b * BCAP + r] =
                    (unsigned)sr[k] | ((unsigned)(dr[k] & 255) << 16);
        }
    }
}

// exclusive scan of gbc[NBK] -> bbase[0..NBK]; off[NN] = ETOT
__global__ __launch_bounds__(256) void k_bscan(const int* __restrict__ gbc,
                                               int* __restrict__ bbase,
                                               int* __restrict__ off_last) {
    const int t = threadIdx.x;
    const int v = (t < NBK) ? gbc[t] : 0;
    int incl = v;
#pragma unroll
    for (int o = 1; o < 64; o <<= 1) {
        int u = __shfl_up(incl, o);
        if ((t & 63) >= o) incl += u;
    }
    __shared__ int ws[4], wsx[4];
    if ((t & 63) == 63) ws[t >> 6] = incl;
    __syncthreads();
    if (t == 0) {
        int r = 0;
#pragma unroll
        for (int i = 0; i < 4; ++i) { wsx[i] = r; r += ws[i]; }
        bbase[NBK] = r;
        off_last[0] = r;            // == ETOT
    }
    __syncthreads();
    if (t < NBK) bbase[t] = incl - v + wsx[t >> 6];
}

// ---------------------------------------------------------------------------
// binB: one block per bucket. Per-node counts come from cnt[] (built in
// binA) -> 256-scan -> off/lcur; single placement pass over binb.
// ---------------------------------------------------------------------------
__global__ __launch_bounds__(BTH) void k_binB(const unsigned* __restrict__ binb,
                                              const int* __restrict__ gbc,
                                              const int* __restrict__ bbase,
                                              const int* __restrict__ cnt,
                                              const float2* __restrict__ asrc,
                                              const float2* __restrict__ adst,
                                              int* __restrict__ off,
                                              unsigned short* __restrict__ srcs16,
                                              unsigned* __restrict__ wpk) {
    __shared__ int lcur[256];
    __shared__ int ws[4], wsx[4];
    const int b = blockIdx.x;
    const int t = threadIdx.x;
    int n = gbc[b];
    if (n > BCAP) n = BCAP;
    const int base = bbase[b];
    const unsigned* bb = binb + (size_t)b * BCAP;

    // 256-wide exclusive scan of this bucket's per-node counts
    int v = 0, incl = 0;
    if (t < 256) {
        const int nd = b * 256 + t;
        v = (nd < NN) ? cnt[nd] : 0;
        incl = v;
#pragma unroll
        for (int o = 1; o < 64; o <<= 1) {
            int u = __shfl_up(incl, o);
            if ((t & 63) >= o) incl += u;
        }
        if ((t & 63) == 63) ws[t >> 6] = incl;
    }
    __syncthreads();
    if (t == 0) {
        int r = 0;
#pragma unroll
        for (int i = 0; i < 4; ++i) { wsx[i] = r; r += ws[i]; }
    }
    __syncthreads();
    if (t < 256) {
        const int excl = incl - v + wsx[t >> 6];
        lcur[t] = excl;
        const int nd = b * 256 + t;
        if (nd < NN) off[nd] = base + excl;
    }
    __syncthreads();

    for (int i = t; i < n; i += BTH) {
        const unsigned pk = bb[i];
        const int s    = (int)(pk & 0xffffu);
        const int dlow = (int)((pk >> 16) & 255);
        const int pos  = base + atomicAdd(&lcur[dlow], 1);
        const float2 as = asrc[s];
        const float2 ad = adst[b * 256 + dlow];
        float v0 = as.x + ad.x;
        float v1 = as.y + ad.y;
        v0 = v0 > 0.f ? v0 : 0.2f * v0;
        v1 = v1 > 0.f ? v1 : 0.2f * v1;
        srcs16[pos] = (unsigned short)s;
        wpk[pos] = packbf(exp2f(v0), exp2f(v1));
    }
}

// ---------------------------------------------------------------------------
// agg (round-10 proven form): one 64-lane wave per node; half-waves process
// different edge-parities (uint2 = 2 channels/lane); 8-wide unroll -> 16
// independent gather chains per wave. Tail clamp+masked.
// ---------------------------------------------------------------------------
__global__ __launch_bounds__(256) void k_agg(const int* __restrict__ off,
                                             const unsigned short* __restrict__ srcs16,
                                             const unsigned* __restrict__ wpk,
                                             const uint2* __restrict__ hbuf2,
                                             const float2* __restrict__ bias2,
                                             float2* __restrict__ out2) {
    const int wid = (int)((blockIdx.x * 256 + threadIdx.x) >> 6);
    const int lane = threadIdx.x & 63;
    if (wid >= NN) return;
    const int half = lane >> 5;          // edge-parity this lane serves
    const int sl   = lane & 31;          // channel pair index
    const int beg = off[wid];
    const int end = off[wid + 1];

    float a0x = 0.f, a1x = 0.f, a0y = 0.f, a1y = 0.f, D0 = 0.f, D1 = 0.f;

    for (int i = beg + half; i < end; i += 16) {
        unsigned s[8], w[8];
        uint2 p[8];
        int e[8];
#pragma unroll
        for (int j = 0; j < 8; ++j) {
            e[j] = i + 2 * j;
            const int ec = e[j] < end ? e[j] : end - 1;   // clamp (hot line)
            s[j] = srcs16[ec];
        }
#pragma unroll
        for (int j = 0; j < 8; ++j) p[j] = hbuf2[(s[j] << 5) | sl];
#pragma unroll
        for (int j = 0; j < 8; ++j) {
            const int ec = e[j] < end ? e[j] : end - 1;
            w[j] = wpk[ec];
            if (e[j] >= end) w[j] = 0;                    // mask tail
        }
#pragma unroll
        for (int j = 0; j < 8; ++j) {
            const float w0 = __uint_as_float(w[j] << 16);
            const float w1 = __uint_as_float(w[j] & 0xffff0000u);
            a0x += w0 * __uint_as_float(p[j].x << 16);
            a1x += w1 * __uint_as_float(p[j].x & 0xffff0000u);
            a0y += w0 * __uint_as_float(p[j].y << 16);
            a1y += w1 * __uint_as_float(p[j].y & 0xffff0000u);
            D0 += w0;
            D1 += w1;
        }
    }

    // combine the two edge-parity halves (lane l <-> l^32 hold same channels)
    a0x += __shfl_xor(a0x, 32);
    a1x += __shfl_xor(a1x, 32);
    a0y += __shfl_xor(a0y, 32);
    a1y += __shfl_xor(a1y, 32);
    D0  += __shfl_xor(D0, 32);
    D1  += __shfl_xor(D1, 32);

    if (half == 0) {
        const float2 bv = bias2[sl];
        out2[(size_t)wid * 32 + sl] =
            make_float2(bv.x + 0.5f * (a0x / D0 + a1x / D1),
                        bv.y + 0.5f * (a0y / D0 + a1y / D1));
    }
}

extern "C" void kernel_launch(void* const* d_in, const int* in_sizes, int n_in,
                              void* d_out, int out_size, void* d_ws, size_t ws_size,
                              hipStream_t stream) {
    const float* x       = (const float*)d_in[0];
    const float* W       = (const float*)d_in[1];
    const float* att_src = (const float*)d_in[2];
    const float* att_dst = (const float*)d_in[3];
    const float* bias    = (const float*)d_in[4];
    const int*   ei      = (const int*)d_in[5];
    float* out = (float*)d_out;

    char* ws = (char*)d_ws;
    unsigned*       hbuf   = (unsigned*)(ws + OFF_HBUF);
    float2*         asrc   = (float2*)(ws + OFF_ASRC);
    float2*         adst   = (float2*)(ws + OFF_ADST);
    int*            gbc    = (int*)(ws + OFF_GBC);
    int*            bbase  = (int*)(ws + OFF_BBASE);
    int*            off    = (int*)(ws + OFF_OFF);
    int*            cnt    = (int*)(ws + OFF_CNT);
    unsigned short* srcs16 = (unsigned short*)(ws + OFF_SRC16);
    unsigned*       wpk    = (unsigned*)(ws + OFF_WPK);
    unsigned*       binb   = (unsigned*)(ws + OFF_BINB);

    k_proj<<<(NN + 63) / 64, 256, 0, stream>>>(x, W, att_src, att_dst, hbuf,
                                               asrc, adst, gbc, cnt);
    k_binA<<<(ETOT + EPB - 1) / EPB, 256, 0, stream>>>(ei, gbc, cnt, binb);
    k_bscan<<<1, 256, 0, stream>>>(gbc, bbase, off + NN);
    k_binB<<<NBK, BTH, 0, stream>>>(binb, gbc, bbase, cnt, asrc, adst,
                                    off, srcs16, wpk);
    k_agg<<<(NN * 64 + 255) / 256, 256, 0, stream>>>(off, srcs16, wpk,
                                                     (const uint2*)hbuf,
                                                     (const float2*)bias,
                                                     (float2*)out);
}

// Round 14
// 97.399 us; speedup vs baseline: 1.2675x; 1.2675x over previous
//
#include <hip/hip_runtime.h>

#define NN 50000
#define NE 800000
#define ETOT (NE + NN)           // 850000 incl. self-loops
#define INCH 128
#define OUTC 64
#define LOG2E 1.44269504088896f
#define NBK 196                  // dst buckets (dst>>8), 256 nodes each
#define BCAP 5120                // bucket capacity (avg 4352, sigma 64)
#define EPB 1024                 // edges per binA block
#define BTH 1024                 // binB block size (BCAP/BTH = 5 unroll)

// ---------------- workspace layout (bytes) ----------------
// hbuf : uint[NN*64]     @ 0           (12,800,000)  packed bf16 (h0 lo, h1 hi)
// asrc : float2[NN]      @ 12,800,000  (400,000)     (pre-scaled by log2e)
// adst : float2[NN]      @ 13,200,000  (400,000)     (pre-scaled by log2e)
// gbc  : int[NBK]        @ 13,600,000  (1,024)       (zeroed by k_proj blk 0)
// bbase: int[NBK+1]      @ 13,601,024  (1,024)
// off  : int[NN+1]       @ 13,602,048  (200,004+pad)
// wrec : uint2[ETOT]     @ 13,802,056  (6,800,000)   .x = s | w0bits<<16, .y = w1bits<<16
// binb : uint[NBK*BCAP]  @ 20,602,056  (4,014,080)   s | (d&255)<<16
#define OFF_HBUF  0
#define OFF_ASRC  12800000
#define OFF_ADST  13200000
#define OFF_GBC   13600000
#define OFF_BBASE 13601024
#define OFF_OFF   13602048
#define OFF_WREC  13802056
#define OFF_BINB  20602056

typedef __attribute__((ext_vector_type(8))) short short8v;   // 8 bf16 (4 VGPR)
typedef __attribute__((ext_vector_type(4))) float float4v;   // MFMA acc
typedef unsigned long long ull;

__device__ __forceinline__ unsigned short f2bf(float f) {
    unsigned u = __float_as_uint(f);
    u += 0x7fffu + ((u >> 16) & 1u);   // round-to-nearest-even
    return (unsigned short)(u >> 16);
}
__device__ __forceinline__ unsigned packbf(float a, float b) {
    return (unsigned)f2bf(a) | ((unsigned)f2bf(b) << 16);
}

// ---------------------------------------------------------------------------
// MFMA projection: h = x@W (bf16 in, fp32 acc), packed bf16 hbuf out
// (interleaved [node][64ch]), attention dots pre-scaled by log2e.
// Block 0 also zeroes gbc (k_binA runs strictly after k_proj).
// ---------------------------------------------------------------------------
#define PITCH 272
#define XLDS_BYTES (64 * PITCH)
#define WT_OFF XLDS_BYTES
#define SMEM_BYTES (XLDS_BYTES + 128 * PITCH)  // 52224

__global__ __launch_bounds__(256) void k_proj(const float* __restrict__ x,
                                              const float* __restrict__ W,
                                              const float* __restrict__ att_src,
                                              const float* __restrict__ att_dst,
                                              unsigned* __restrict__ hbuf,
                                              float2* __restrict__ asrc,
                                              float2* __restrict__ adst,
                                              int* __restrict__ gbc) {
    __shared__ char smem[SMEM_BYTES];
    const int t = threadIdx.x;
    const int nbase = blockIdx.x * 64;

    if (blockIdx.x == 0 && t < NBK) gbc[t] = 0;

    // ---- stage x-tile (64 rows x 128 k) as bf16, pitch 272 ----
    {
        const int rl = t >> 2;
        const int q  = t & 3;
        int rg = nbase + rl;
        if (rg >= NN) rg = NN - 1;
        const float4* src = (const float4*)(x + (size_t)rg * INCH + q * 32);
        char* dst = smem + rl * PITCH + q * 64;
#pragma unroll
        for (int i = 0; i < 8; ++i) {
            const float4 v = src[i];
            const unsigned lo = packbf(v.x, v.y);
            const unsigned hi = packbf(v.z, v.w);
            *(ull*)(dst + i * 8) = (ull)lo | ((ull)hi << 32);
        }
    }
    // ---- stage W^T (128 cols x 128 k) as bf16, pitch 272 ----
    {
        const int c  = t & 127;
        const int kh = t >> 7;
        const float* wcol = W + c;
        char* dst = smem + WT_OFF + c * PITCH + kh * 128;
#pragma unroll
        for (int i = 0; i < 16; ++i) {
            const int k = kh * 64 + i * 4;
            const float w0 = wcol[(size_t)(k + 0) * 128];
            const float w1 = wcol[(size_t)(k + 1) * 128];
            const float w2 = wcol[(size_t)(k + 2) * 128];
            const float w3 = wcol[(size_t)(k + 3) * 128];
            const unsigned lo = packbf(w0, w1);
            const unsigned hi = packbf(w2, w3);
            *(ull*)(dst + i * 8) = (ull)lo | ((ull)hi << 32);
        }
    }
    __syncthreads();

    const int w  = t >> 6;
    const int l  = t & 63;
    const int li = l & 15;
    const int g  = l >> 4;

    const char* xb = smem + (w * 16 + li) * PITCH + g * 16;
    const char* wb = smem + WT_OFF + li * PITCH + g * 16;

    float4v acc[8] = {};
#pragma unroll
    for (int ks = 0; ks < 4; ++ks) {
        const short8v aF = *(const short8v*)(xb + ks * 64);
#pragma unroll
        for (int nt = 0; nt < 8; ++nt) {
            const short8v bF = *(const short8v*)(wb + nt * (16 * PITCH) + ks * 64);
            acc[nt] = __builtin_amdgcn_mfma_f32_16x16x32_bf16(aF, bF, acc[nt], 0, 0, 0);
        }
    }

    float aS0[4], aS1[4], aD0[4], aD1[4];
#pragma unroll
    for (int tt = 0; tt < 4; ++tt) {
        aS0[tt] = att_src[tt * 16 + li];
        aS1[tt] = att_src[64 + tt * 16 + li];
        aD0[tt] = att_dst[tt * 16 + li];
        aD1[tt] = att_dst[64 + tt * 16 + li];
    }
#pragma unroll
    for (int r = 0; r < 4; ++r) {
        const int n = nbase + w * 16 + g * 4 + r;
        const bool valid = (n < NN);
        float ps0 = 0.f, ps1 = 0.f, pd0 = 0.f, pd1 = 0.f;
#pragma unroll
        for (int tt = 0; tt < 4; ++tt) {
            const float h0 = acc[tt][r];
            const float h1 = acc[tt + 4][r];
            if (valid) hbuf[(size_t)n * 64 + tt * 16 + li] = packbf(h0, h1);
            ps0 += h0 * aS0[tt];
            ps1 += h1 * aS1[tt];
            pd0 += h0 * aD0[tt];
            pd1 += h1 * aD1[tt];
        }
#pragma unroll
        for (int m = 1; m <= 8; m <<= 1) {
            ps0 += __shfl_xor(ps0, m);
            ps1 += __shfl_xor(ps1, m);
            pd0 += __shfl_xor(pd0, m);
            pd1 += __shfl_xor(pd1, m);
        }
        if (valid && li == 0) {
            asrc[n] = make_float2(ps0 * LOG2E, ps1 * LOG2E);
            adst[n] = make_float2(pd0 * LOG2E, pd1 * LOG2E);
        }
    }
}

// ---------------------------------------------------------------------------
// binA (round-10 form): edges cached in registers, LDS bucket histogram,
// reserve chunks in gbc, write packed uint (s | dlow<<16) into bucket regions.
// ---------------------------------------------------------------------------
__global__ __launch_bounds__(256) void k_binA(const int* __restrict__ ei,
                                              int* __restrict__ gbc,
                                              unsigned* __restrict__ binb) {
    __shared__ int lcnt[NBK];
    __shared__ int lbase[NBK];
    const int t = threadIdx.x;
    const int e0 = blockIdx.x * EPB;

    for (int i = t; i < NBK; i += 256) lcnt[i] = 0;
    __syncthreads();

    int sr[EPB / 256], dr[EPB / 256];
#pragma unroll
    for (int k = 0; k < EPB / 256; ++k) {
        const int e = e0 + k * 256 + t;
        if (e < ETOT) {
            int s, d;
            if (e < NE) { s = ei[e]; d = ei[NE + e]; }
            else        { s = d = e - NE; }
            sr[k] = s; dr[k] = d;
            atomicAdd(&lcnt[d >> 8], 1);
        } else {
            sr[k] = -1; dr[k] = 0;
        }
    }
    __syncthreads();
    for (int i = t; i < NBK; i += 256) {
        const int c = lcnt[i];
        lbase[i] = c ? atomicAdd(&gbc[i], c) : 0;
        lcnt[i] = 0;
    }
    __syncthreads();
#pragma unroll
    for (int k = 0; k < EPB / 256; ++k) {
        if (sr[k] >= 0) {
            const int b = dr[k] >> 8;
            const int r = lbase[b] + atomicAdd(&lcnt[b], 1);
            if (r < BCAP)
                binb[(size_t)b * BCAP + r] =
                    (unsigned)sr[k] | ((unsigned)(dr[k] & 255) << 16);
        }
    }
}

// exclusive scan of gbc[NBK] -> bbase[0..NBK]; off[NN] = ETOT
__global__ __launch_bounds__(256) void k_bscan(const int* __restrict__ gbc,
                                               int* __restrict__ bbase,
                                               int* __restrict__ off_last) {
    const int t = threadIdx.x;
    const int v = (t < NBK) ? gbc[t] : 0;
    int incl = v;
#pragma unroll
    for (int o = 1; o < 64; o <<= 1) {
        int u = __shfl_up(incl, o);
        if ((t & 63) >= o) incl += u;
    }
    __shared__ int ws[4], wsx[4];
    if ((t & 63) == 63) ws[t >> 6] = incl;
    __syncthreads();
    if (t == 0) {
        int r = 0;
#pragma unroll
        for (int i = 0; i < 4; ++i) { wsx[i] = r; r += ws[i]; }
        bbase[NBK] = r;
        off_last[0] = r;            // == ETOT
    }
    __syncthreads();
    if (t < NBK) bbase[t] = incl - v + wsx[t >> 6];
}

// ---------------------------------------------------------------------------
// binB: one block per bucket. Histogram pass over binb + 256-scan -> off,
// then a 5-wide statically-unrolled placement pass (independent asrc chains),
// adst served from LDS, single 8B wrec store per edge.
// ---------------------------------------------------------------------------
__global__ __launch_bounds__(BTH) void k_binB(const unsigned* __restrict__ binb,
                                              const int* __restrict__ gbc,
                                              const int* __restrict__ bbase,
                                              const float2* __restrict__ asrc,
                                              const float2* __restrict__ adst,
                                              int* __restrict__ off,
                                              uint2* __restrict__ wrec) {
    __shared__ int lcnt[256];
    __shared__ int lcur[256];
    __shared__ float2 lad[256];
    __shared__ int ws[4], wsx[4];
    const int b = blockIdx.x;
    const int t = threadIdx.x;
    int n = gbc[b];
    if (n > BCAP) n = BCAP;
    const int base = bbase[b];
    const unsigned* bb = binb + (size_t)b * BCAP;

    if (t < 256) {
        lcnt[t] = 0;
        const int nd = b * 256 + t;
        lad[t] = (nd < NN) ? adst[nd] : make_float2(0.f, 0.f);
    }
    __syncthreads();

    for (int i = t; i < n; i += BTH)
        atomicAdd(&lcnt[(bb[i] >> 16) & 255], 1);
    __syncthreads();

    // 256-wide exclusive scan (first 4 waves)
    int v = 0, incl = 0;
    if (t < 256) {
        v = lcnt[t];
        incl = v;
#pragma unroll
        for (int o = 1; o < 64; o <<= 1) {
            int u = __shfl_up(incl, o);
            if ((t & 63) >= o) incl += u;
        }
        if ((t & 63) == 63) ws[t >> 6] = incl;
    }
    __syncthreads();
    if (t == 0) {
        int r = 0;
#pragma unroll
        for (int i = 0; i < 4; ++i) { wsx[i] = r; r += ws[i]; }
    }
    __syncthreads();
    if (t < 256) {
        const int excl = incl - v + wsx[t >> 6];
        lcur[t] = excl;
        const int nd = b * 256 + t;
        if (nd < NN) off[nd] = base + excl;
    }
    __syncthreads();

    // ---- placement: 5-wide static unroll (BCAP/BTH = 5), batched loads ----
    unsigned pk[5];
    bool valid[5];
#pragma unroll
    for (int j = 0; j < 5; ++j) {
        const int i = t + j * BTH;
        valid[j] = (i < n);
        pk[j] = valid[j] ? bb[i] : 0u;
    }
    int s[5];
    float2 as[5];
#pragma unroll
    for (int j = 0; j < 5; ++j) s[j] = (int)(pk[j] & 0xffffu);
#pragma unroll
    for (int j = 0; j < 5; ++j) as[j] = asrc[s[j]];    // 5 independent gathers
#pragma unroll
    for (int j = 0; j < 5; ++j) {
        if (valid[j]) {
            const int dlow = (int)((pk[j] >> 16) & 255);
            const float2 ad = lad[dlow];
            float v0 = as[j].x + ad.x;
            float v1 = as[j].y + ad.y;
            v0 = v0 > 0.f ? v0 : 0.2f * v0;
            v1 = v1 > 0.f ? v1 : 0.2f * v1;
            const int pos = base + atomicAdd(&lcur[dlow], 1);
            wrec[pos] = make_uint2((unsigned)s[j] | ((unsigned)f2bf(exp2f(v0)) << 16),
                                   (unsigned)f2bf(exp2f(v1)) << 16);
        }
    }
}

// ---------------------------------------------------------------------------
// agg (round-10 proven form, wrec-packed): one 64-lane wave per node;
// half-waves process different edge-parities (uint2 = 2 channels/lane);
// 8-wide unroll -> 16 independent gather chains per wave. Tail clamp+masked.
// ---------------------------------------------------------------------------
__global__ __launch_bounds__(256) void k_agg(const int* __restrict__ off,
                                             const uint2* __restrict__ wrec,
                                             const uint2* __restrict__ hbuf2,
                                             const float2* __restrict__ bias2,
                                             float2* __restrict__ out2) {
    const int wid = (int)((blockIdx.x * 256 + threadIdx.x) >> 6);
    const int lane = threadIdx.x & 63;
    if (wid >= NN) return;
    const int half = lane >> 5;          // edge-parity this lane serves
    const int sl   = lane & 31;          // channel pair index
    const int beg = off[wid];
    const int end = off[wid + 1];

    float a0x = 0.f, a1x = 0.f, a0y = 0.f, a1y = 0.f, D0 = 0.f, D1 = 0.f;

    for (int i = beg + half; i < end; i += 16) {
        uint2 r[8], p[8];
        int e[8];
#pragma unroll
        for (int j = 0; j < 8; ++j) {
            e[j] = i + 2 * j;
            const int ec = e[j] < end ? e[j] : end - 1;   // clamp (hot line)
            r[j] = wrec[ec];
        }
#pragma unroll
        for (int j = 0; j < 8; ++j)
            p[j] = hbuf2[((r[j].x & 0xffffu) << 5) | sl];
#pragma unroll
        for (int j = 0; j < 8; ++j) {
            if (e[j] >= end) { r[j].x &= 0xffffu; r[j].y = 0u; }  // mask tail
        }
#pragma unroll
        for (int j = 0; j < 8; ++j) {
            const float w0 = __uint_as_float(r[j].x & 0xffff0000u);
            const float w1 = __uint_as_float(r[j].y);
            a0x += w0 * __uint_as_float(p[j].x << 16);
            a1x += w1 * __uint_as_float(p[j].x & 0xffff0000u);
            a0y += w0 * __uint_as_float(p[j].y << 16);
            a1y += w1 * __uint_as_float(p[j].y & 0xffff0000u);
            D0 += w0;
            D1 += w1;
        }
    }

    // combine the two edge-parity halves (lane l <-> l^32 hold same channels)
    a0x += __shfl_xor(a0x, 32);
    a1x += __shfl_xor(a1x, 32);
    a0y += __shfl_xor(a0y, 32);
    a1y += __shfl_xor(a1y, 32);
    D0  += __shfl_xor(D0, 32);
    D1  += __shfl_xor(D1, 32);

    if (half == 0) {
        const float2 bv = bias2[sl];
        out2[(size_t)wid * 32 + sl] =
            make_float2(bv.x + 0.5f * (a0x / D0 + a1x / D1),
                        bv.y + 0.5f * (a0y / D0 + a1y / D1));
    }
}

extern "C" void kernel_launch(void* const* d_in, const int* in_sizes, int n_in,
                              void* d_out, int out_size, void* d_ws, size_t ws_size,
                              hipStream_t stream) {
    const float* x       = (const float*)d_in[0];
    const float* W       = (const float*)d_in[1];
    const float* att_src = (const float*)d_in[2];
    const float* att_dst = (const float*)d_in[3];
    const float* bias    = (const float*)d_in[4];
    const int*   ei      = (const int*)d_in[5];
    float* out = (float*)d_out;

    char* ws = (char*)d_ws;
    unsigned* hbuf  = (unsigned*)(ws + OFF_HBUF);
    float2*   asrc  = (float2*)(ws + OFF_ASRC);
    float2*   adst  = (float2*)(ws + OFF_ADST);
    int*      gbc   = (int*)(ws + OFF_GBC);
    int*      bbase = (int*)(ws + OFF_BBASE);
    int*      off   = (int*)(ws + OFF_OFF);
    uint2*    wrec  = (uint2*)(ws + OFF_WREC);
    unsigned* binb  = (unsigned*)(ws + OFF_BINB);

    k_proj<<<(NN + 63) / 64, 256, 0, stream>>>(x, W, att_src, att_dst, hbuf,
                                               asrc, adst, gbc);
    k_binA<<<(ETOT + EPB - 1) / EPB, 256, 0, stream>>>(ei, gbc, binb);
    k_bscan<<<1, 256, 0, stream>>>(gbc, bbase, off + NN);
    k_binB<<<NBK, BTH, 0, stream>>>(binb, gbc, bbase, asrc, adst, off, wrec);
    k_agg<<<(NN * 64 + 255) / 256, 256, 0, stream>>>(off, wrec,
                                                     (const uint2*)hbuf,
                                                     (const float2*)bias,
                                                     (float2*)out);
}

// Round 15
// 92.333 us; speedup vs baseline: 1.3371x; 1.0549x over previous
//
#include <hip/hip_runtime.h>

#define NN 50000
#define NE 800000
#define ETOT (NE + NN)           // 850000 incl. self-loops
#define INCH 128
#define OUTC 64
#define LOG2E 1.44269504088896f
#define NBK 196                  // dst buckets (dst>>8), 256 nodes each
#define BCAP 5120                // bucket capacity (avg 4352, sigma 64)
#define EPB 1024                 // edges per binA block
#define BTH 1024                 // binB block size

// ---------------- workspace layout (bytes) ----------------
// hbuf  : uint[NN*64]     @ 0           (12,800,000)  packed bf16 (h0 lo, h1 hi)
// asrc  : float2[NN]      @ 12,800,000  (400,000)     (pre-scaled by log2e)
// adst  : float2[NN]      @ 13,200,000  (400,000)     (pre-scaled by log2e)
// gbc   : int[NBK]        @ 13,600,000  (1,024)       (zeroed by k_proj blk 0)
// off   : int[NN+1]       @ 13,602,048  (200,004)
// srcs16: ushort[ETOT]    @ 13,803,204  (1,700,000)
// wpk   : uint[ETOT]      @ 15,503,204  (3,400,000)   packed bf16 (w0 lo, w1 hi)
// binb  : uint[NBK*BCAP]  @ 18,903,204  (4,014,080)   s | (d&255)<<16
#define OFF_HBUF  0
#define OFF_ASRC  12800000
#define OFF_ADST  13200000
#define OFF_GBC   13600000
#define OFF_OFF   13602048
#define OFF_SRC16 13803204
#define OFF_WPK   15503204
#define OFF_BINB  18903204

typedef __attribute__((ext_vector_type(8))) short short8v;   // 8 bf16 (4 VGPR)
typedef __attribute__((ext_vector_type(4))) float float4v;   // MFMA acc
typedef unsigned long long ull;

__device__ __forceinline__ unsigned short f2bf(float f) {
    unsigned u = __float_as_uint(f);
    u += 0x7fffu + ((u >> 16) & 1u);   // round-to-nearest-even
    return (unsigned short)(u >> 16);
}
__device__ __forceinline__ unsigned packbf(float a, float b) {
    return (unsigned)f2bf(a) | ((unsigned)f2bf(b) << 16);
}

// ---------------------------------------------------------------------------
// MFMA projection: h = x@W (bf16 in, fp32 acc), packed bf16 hbuf out
// (interleaved [node][64ch]), attention dots pre-scaled by log2e.
// Block 0 also zeroes gbc (k_binA runs strictly after k_proj).
// ---------------------------------------------------------------------------
#define PITCH 272
#define XLDS_BYTES (64 * PITCH)
#define WT_OFF XLDS_BYTES
#define SMEM_BYTES (XLDS_BYTES + 128 * PITCH)  // 52224

__global__ __launch_bounds__(256) void k_proj(const float* __restrict__ x,
                                              const float* __restrict__ W,
                                              const float* __restrict__ att_src,
                                              const float* __restrict__ att_dst,
                                              unsigned* __restrict__ hbuf,
                                              float2* __restrict__ asrc,
                                              float2* __restrict__ adst,
                                              int* __restrict__ gbc) {
    __shared__ char smem[SMEM_BYTES];
    const int t = threadIdx.x;
    const int nbase = blockIdx.x * 64;

    if (blockIdx.x == 0 && t < NBK) gbc[t] = 0;

    // ---- stage x-tile (64 rows x 128 k) as bf16, pitch 272 ----
    {
        const int rl = t >> 2;
        const int q  = t & 3;
        int rg = nbase + rl;
        if (rg >= NN) rg = NN - 1;
        const float4* src = (const float4*)(x + (size_t)rg * INCH + q * 32);
        char* dst = smem + rl * PITCH + q * 64;
#pragma unroll
        for (int i = 0; i < 8; ++i) {
            const float4 v = src[i];
            const unsigned lo = packbf(v.x, v.y);
            const unsigned hi = packbf(v.z, v.w);
            *(ull*)(dst + i * 8) = (ull)lo | ((ull)hi << 32);
        }
    }
    // ---- stage W^T (128 cols x 128 k) as bf16, pitch 272 ----
    {
        const int c  = t & 127;
        const int kh = t >> 7;
        const float* wcol = W + c;
        char* dst = smem + WT_OFF + c * PITCH + kh * 128;
#pragma unroll
        for (int i = 0; i < 16; ++i) {
            const int k = kh * 64 + i * 4;
            const float w0 = wcol[(size_t)(k + 0) * 128];
            const float w1 = wcol[(size_t)(k + 1) * 128];
            const float w2 = wcol[(size_t)(k + 2) * 128];
            const float w3 = wcol[(size_t)(k + 3) * 128];
            const unsigned lo = packbf(w0, w1);
            const unsigned hi = packbf(w2, w3);
            *(ull*)(dst + i * 8) = (ull)lo | ((ull)hi << 32);
        }
    }
    __syncthreads();

    const int w  = t >> 6;
    const int l  = t & 63;
    const int li = l & 15;
    const int g  = l >> 4;

    const char* xb = smem + (w * 16 + li) * PITCH + g * 16;
    const char* wb = smem + WT_OFF + li * PITCH + g * 16;

    float4v acc[8] = {};
#pragma unroll
    for (int ks = 0; ks < 4; ++ks) {
        const short8v aF = *(const short8v*)(xb + ks * 64);
#pragma unroll
        for (int nt = 0; nt < 8; ++nt) {
            const short8v bF = *(const short8v*)(wb + nt * (16 * PITCH) + ks * 64);
            acc[nt] = __builtin_amdgcn_mfma_f32_16x16x32_bf16(aF, bF, acc[nt], 0, 0, 0);
        }
    }

    float aS0[4], aS1[4], aD0[4], aD1[4];
#pragma unroll
    for (int tt = 0; tt < 4; ++tt) {
        aS0[tt] = att_src[tt * 16 + li];
        aS1[tt] = att_src[64 + tt * 16 + li];
        aD0[tt] = att_dst[tt * 16 + li];
        aD1[tt] = att_dst[64 + tt * 16 + li];
    }
#pragma unroll
    for (int r = 0; r < 4; ++r) {
        const int n = nbase + w * 16 + g * 4 + r;
        const bool valid = (n < NN);
        float ps0 = 0.f, ps1 = 0.f, pd0 = 0.f, pd1 = 0.f;
#pragma unroll
        for (int tt = 0; tt < 4; ++tt) {
            const float h0 = acc[tt][r];
            const float h1 = acc[tt + 4][r];
            if (valid) hbuf[(size_t)n * 64 + tt * 16 + li] = packbf(h0, h1);
            ps0 += h0 * aS0[tt];
            ps1 += h1 * aS1[tt];
            pd0 += h0 * aD0[tt];
            pd1 += h1 * aD1[tt];
        }
#pragma unroll
        for (int m = 1; m <= 8; m <<= 1) {
            ps0 += __shfl_xor(ps0, m);
            ps1 += __shfl_xor(ps1, m);
            pd0 += __shfl_xor(pd0, m);
            pd1 += __shfl_xor(pd1, m);
        }
        if (valid && li == 0) {
            asrc[n] = make_float2(ps0 * LOG2E, ps1 * LOG2E);
            adst[n] = make_float2(pd0 * LOG2E, pd1 * LOG2E);
        }
    }
}

// ---------------------------------------------------------------------------
// binA: single pass — edges cached in registers, LDS bucket histogram,
// reserve chunks in gbc, write packed uint (s | dlow<<16) into bucket regions.
// ---------------------------------------------------------------------------
__global__ __launch_bounds__(256) void k_binA(const int* __restrict__ ei,
                                              int* __restrict__ gbc,
                                              unsigned* __restrict__ binb) {
    __shared__ int lcnt[NBK];
    __shared__ int lbase[NBK];
    const int t = threadIdx.x;
    const int e0 = blockIdx.x * EPB;

    for (int i = t; i < NBK; i += 256) lcnt[i] = 0;
    __syncthreads();

    int sr[EPB / 256], dr[EPB / 256];
#pragma unroll
    for (int k = 0; k < EPB / 256; ++k) {
        const int e = e0 + k * 256 + t;
        if (e < ETOT) {
            int s, d;
            if (e < NE) { s = ei[e]; d = ei[NE + e]; }
            else        { s = d = e - NE; }
            sr[k] = s; dr[k] = d;
            atomicAdd(&lcnt[d >> 8], 1);
        } else {
            sr[k] = -1; dr[k] = 0;
        }
    }
    __syncthreads();
    for (int i = t; i < NBK; i += 256) {
        const int c = lcnt[i];
        lbase[i] = c ? atomicAdd(&gbc[i], c) : 0;
        lcnt[i] = 0;
    }
    __syncthreads();
#pragma unroll
    for (int k = 0; k < EPB / 256; ++k) {
        if (sr[k] >= 0) {
            const int b = dr[k] >> 8;
            const int r = lbase[b] + atomicAdd(&lcnt[b], 1);
            if (r < BCAP)
                binb[(size_t)b * BCAP + r] =
                    (unsigned)sr[k] | ((unsigned)(dr[k] & 255) << 16);
        }
    }
}

// exclusive scan of gbc[NBK] -> bbase (stored in gbc-adjacent region via off);
// kept as separate tiny kernel (proven fastest form)
__global__ __launch_bounds__(256) void k_bscan(const int* __restrict__ gbc,
                                               int* __restrict__ bbase,
                                               int* __restrict__ off_last) {
    const int t = threadIdx.x;
    const int v = (t < NBK) ? gbc[t] : 0;
    int incl = v;
#pragma unroll
    for (int o = 1; o < 64; o <<= 1) {
        int u = __shfl_up(incl, o);
        if ((t & 63) >= o) incl += u;
    }
    __shared__ int ws[4], wsx[4];
    if ((t & 63) == 63) ws[t >> 6] = incl;
    __syncthreads();
    if (t == 0) {
        int r = 0;
#pragma unroll
        for (int i = 0; i < 4; ++i) { wsx[i] = r; r += ws[i]; }
        bbase[NBK] = r;
        off_last[0] = r;            // == ETOT
    }
    __syncthreads();
    if (t < NBK) bbase[t] = incl - v + wsx[t >> 6];
}

// ---------------------------------------------------------------------------
// binB: one block per bucket. LDS per-node histogram + 256-scan -> off,
// then place srcs16/wpk into the bucket's contiguous CSR window.
// ---------------------------------------------------------------------------
__global__ __launch_bounds__(BTH) void k_binB(const unsigned* __restrict__ binb,
                                              const int* __restrict__ gbc,
                                              const int* __restrict__ bbase,
                                              const float2* __restrict__ asrc,
                                              const float2* __restrict__ adst,
                                              int* __restrict__ off,
                                              unsigned short* __restrict__ srcs16,
                                              unsigned* __restrict__ wpk) {
    __shared__ int lcnt[256];
    __shared__ int lcur[256];
    __shared__ int ws[4], wsx[4];
    const int b = blockIdx.x;
    const int t = threadIdx.x;
    int n = gbc[b];
    if (n > BCAP) n = BCAP;
    const int base = bbase[b];
    const unsigned* bb = binb + (size_t)b * BCAP;

    if (t < 256) lcnt[t] = 0;
    __syncthreads();

    for (int i = t; i < n; i += BTH)
        atomicAdd(&lcnt[(bb[i] >> 16) & 255], 1);
    __syncthreads();

    // 256-wide exclusive scan (first 4 waves)
    int v = 0, incl = 0;
    if (t < 256) {
        v = lcnt[t];
        incl = v;
#pragma unroll
        for (int o = 1; o < 64; o <<= 1) {
            int u = __shfl_up(incl, o);
            if ((t & 63) >= o) incl += u;
        }
        if ((t & 63) == 63) ws[t >> 6] = incl;
    }
    __syncthreads();
    if (t == 0) {
        int r = 0;
#pragma unroll
        for (int i = 0; i < 4; ++i) { wsx[i] = r; r += ws[i]; }
    }
    __syncthreads();
    if (t < 256) {
        const int excl = incl - v + wsx[t >> 6];
        lcur[t] = excl;
        const int nd = b * 256 + t;
        if (nd < NN) off[nd] = base + excl;
    }
    __syncthreads();

    for (int i = t; i < n; i += BTH) {
        const unsigned pk = bb[i];
        const int s    = (int)(pk & 0xffffu);
        const int dlow = (int)((pk >> 16) & 255);
        const int pos  = base + atomicAdd(&lcur[dlow], 1);
        const float2 as = asrc[s];
        const float2 ad = adst[b * 256 + dlow];
        float v0 = as.x + ad.x;
        float v1 = as.y + ad.y;
        v0 = v0 > 0.f ? v0 : 0.2f * v0;
        v1 = v1 > 0.f ? v1 : 0.2f * v1;
        srcs16[pos] = (unsigned short)s;
        wpk[pos] = packbf(exp2f(v0), exp2f(v1));
    }
}

// ---------------------------------------------------------------------------
// agg: one 64-lane wave per node; each half-wave (32 lanes, uint2 = 2 channels
// per lane) processes a different edge-parity -> with the 8-wide unroll,
// 16 independent gather chains per wave. Tail is clamp+masked (no serial tail).
// ---------------------------------------------------------------------------
__global__ __launch_bounds__(256) void k_agg(const int* __restrict__ off,
                                             const unsigned short* __restrict__ srcs16,
                                             const unsigned* __restrict__ wpk,
                                             const uint2* __restrict__ hbuf2,
                                             const float2* __restrict__ bias2,
                                             float2* __restrict__ out2) {
    const int wid = (int)((blockIdx.x * 256 + threadIdx.x) >> 6);
    const int lane = threadIdx.x & 63;
    if (wid >= NN) return;
    const int half = lane >> 5;          // edge-parity this lane serves
    const int sl   = lane & 31;          // channel pair index
    const int beg = off[wid];
    const int end = off[wid + 1];

    float a0x = 0.f, a1x = 0.f, a0y = 0.f, a1y = 0.f, D0 = 0.f, D1 = 0.f;

    for (int i = beg + half; i < end; i += 16) {
        unsigned s[8], w[8];
        uint2 p[8];
        int e[8];
#pragma unroll
        for (int j = 0; j < 8; ++j) {
            e[j] = i + 2 * j;
            const int ec = e[j] < end ? e[j] : end - 1;   // clamp (hot line)
            s[j] = srcs16[ec];
        }
#pragma unroll
        for (int j = 0; j < 8; ++j) p[j] = hbuf2[(s[j] << 5) | sl];
#pragma unroll
        for (int j = 0; j < 8; ++j) {
            const int ec = e[j] < end ? e[j] : end - 1;
            w[j] = wpk[ec];
            if (e[j] >= end) w[j] = 0;                    // mask tail
        }
#pragma unroll
        for (int j = 0; j < 8; ++j) {
            const float w0 = __uint_as_float(w[j] << 16);
            const float w1 = __uint_as_float(w[j] & 0xffff0000u);
            a0x += w0 * __uint_as_float(p[j].x << 16);
            a1x += w1 * __uint_as_float(p[j].x & 0xffff0000u);
            a0y += w0 * __uint_as_float(p[j].y << 16);
            a1y += w1 * __uint_as_float(p[j].y & 0xffff0000u);
            D0 += w0;
            D1 += w1;
        }
    }

    // combine the two edge-parity halves (lane l <-> l^32 hold same channels)
    a0x += __shfl_xor(a0x, 32);
    a1x += __shfl_xor(a1x, 32);
    a0y += __shfl_xor(a0y, 32);
    a1y += __shfl_xor(a1y, 32);
    D0  += __shfl_xor(D0, 32);
    D1  += __shfl_xor(D1, 32);

    if (half == 0) {
        const float2 bv = bias2[sl];
        out2[(size_t)wid * 32 + sl] =
            make_float2(bv.x + 0.5f * (a0x / D0 + a1x / D1),
                        bv.y + 0.5f * (a0y / D0 + a1y / D1));
    }
}

extern "C" void kernel_launch(void* const* d_in, const int* in_sizes, int n_in,
                              void* d_out, int out_size, void* d_ws, size_t ws_size,
                              hipStream_t stream) {
    const float* x       = (const float*)d_in[0];
    const float* W       = (const float*)d_in[1];
    const float* att_src = (const float*)d_in[2];
    const float* att_dst = (const float*)d_in[3];
    const float* bias    = (const float*)d_in[4];
    const int*   ei      = (const int*)d_in[5];
    float* out = (float*)d_out;

    char* ws = (char*)d_ws;
    unsigned*       hbuf   = (unsigned*)(ws + OFF_HBUF);
    float2*         asrc   = (float2*)(ws + OFF_ASRC);
    float2*         adst   = (float2*)(ws + OFF_ADST);
    int*            gbc    = (int*)(ws + OFF_GBC);
    int*            off    = (int*)(ws + OFF_OFF);
    unsigned short* srcs16 = (unsigned short*)(ws + OFF_SRC16);
    unsigned*       wpk    = (unsigned*)(ws + OFF_WPK);
    unsigned*       binb   = (unsigned*)(ws + OFF_BINB);
    // bbase reuses the tail of the gbc region (separate 1KB at OFF_GBC+1024 is
    // not laid out; use off+NN+1.. safe spare? -> keep dedicated: place after gbc)
    int* bbase = gbc + 256;   // 196 used of 512-int region (gbc area is 2048B before off)

    k_proj<<<(NN + 63) / 64, 256, 0, stream>>>(x, W, att_src, att_dst, hbuf,
                                               asrc, adst, gbc);
    k_binA<<<(ETOT + EPB - 1) / EPB, 256, 0, stream>>>(ei, gbc, binb);
    k_bscan<<<1, 256, 0, stream>>>(gbc, bbase, off + NN);
    k_binB<<<NBK, BTH, 0, stream>>>(binb, gbc, bbase, asrc, adst, off, srcs16, wpk);
    k_agg<<<(NN * 64 + 255) / 256, 256, 0, stream>>>(off, srcs16, wpk,
                                                     (const uint2*)hbuf,
                                                     (const float2*)bias,
                                                     (float2*)out);
}